// Round 10
// baseline (57.070 us; speedup 1.0000x reference)
//
#include <hip/hip_runtime.h>
#include <math.h>

#define E 8
#define DF 512
#define DE 128
#define H 8
#define S 64
#define GH 16
#define HD 16
#define B 2
#define NTOK 1024
#define KMAX 256      // staged key capacity (c ~ Binom(1024,1/8); c>192 is ~6 sigma)

__device__ __forceinline__ float wave_sum(float v) {
#pragma unroll
    for (int m = 32; m; m >>= 1) v += __shfl_xor(v, m, 64);
    return v;
}

// ---- kernel 1: prep = lists (0-7) | WfT (8-23) | LN+gate+QKV (24-535, 1 token/wave) ----
// QKV reads ORIGINAL Wq/Wk/Wv [E][DE][S] layout, phased per matrix (L1-resident 32 KB each).
__global__ __launch_bounds__(256) void k_prep(
    const float* __restrict__ Wq, const float* __restrict__ Wk,
    const float* __restrict__ Wv, const float* __restrict__ Wf,
    const float* __restrict__ fp, const float* __restrict__ x,
    const float* __restrict__ lnw, const float* __restrict__ lnb,
    const float* __restrict__ alpha,
    const float* __restrict__ Wg1, const float* __restrict__ bg1,
    const float* __restrict__ Wg2, const float* __restrict__ bg2,
    float* __restrict__ WfT, unsigned* __restrict__ cnt,
    unsigned* __restrict__ lst,
    float* __restrict__ Q, float* __restrict__ K, float* __restrict__ V) {
    __shared__ __align__(16) float sh[64][65];
    int bid = blockIdx.x, tid = threadIdx.x;
    if (bid < 8) {                        // expert token lists (1 wave)
        if (tid >= 64) return;
        int e = bid, l = tid;
        unsigned c = 0;
        for (int base = 0; base < NTOK; base += 64) {
            int n = base + l;
            int ee = (int)(fp[n] * 8.0f);
            ee = ee > 7 ? 7 : ee;
            bool in = (ee == e);
            unsigned long long m = __ballot(in);
            unsigned pos = (unsigned)__popcll(m & ((1ull << l) - 1ull));
            if (in) lst[e * NTOK + c + pos] = (unsigned)n;
            c += (unsigned)__popcll(m);
        }
        if (l == 0) cnt[e] = c;
        return;
    }
    if (bid < 24) {                       // Wf [512][128] -> WfT [128][512]
        int i = bid - 8, rt = i >> 1, ct2 = i & 1;
        const float* in = Wf + (size_t)rt * 64 * DE + ct2 * 64;
        float* outp = WfT + (size_t)ct2 * 64 * DF + rt * 64;
        int cc = tid & 63, r0 = tid >> 6;
        for (int r = r0; r < 64; r += 4) sh[r][cc] = in[(size_t)r * DE + cc];
        __syncthreads();
        for (int c2 = r0; c2 < 64; c2 += 4)
            outp[(size_t)c2 * DF + cc] = sh[cc][c2];
        return;
    }
    // ---- LN + gate + QKV, 1 token per wave ----
    float (*fsh)[64] = (float(*)[64])sh;  // wave-private slabs [4][64]
    int wave = tid >> 6, lane = tid & 63;
    int t = (bid - 24) * 4 + wave;        // 0..2047
    int n = t & (NTOK - 1);
    const float* xr = x + (size_t)t * DF;
    float4 a  = *(const float4*)(xr + lane * 8);
    float4 b4 = *(const float4*)(xr + lane * 8 + 4);
    float s  = a.x + a.y + a.z + a.w + b4.x + b4.y + b4.z + b4.w;
    float ss = a.x*a.x + a.y*a.y + a.z*a.z + a.w*a.w
             + b4.x*b4.x + b4.y*b4.y + b4.z*b4.z + b4.w*b4.w;
    s = wave_sum(s);
    ss = wave_sum(ss);
    float mu  = s * (1.0f / DF);
    float var = ss * (1.0f / DF) - mu * mu;
    float rs  = rsqrtf(var + 1e-5f);
    int e = (int)(fp[n] * 8.0f);
    e = e > 7 ? 7 : e;
    float f = (xr[e * 64 + lane] - mu) * rs * lnw[e * 64 + lane]
            + lnb[e * 64 + lane];
    fsh[wave][lane] = f;
    __syncthreads();
    // gate: lane -> (h = lane&15, si-quarter = lane>>4)
    int hh = lane & 15, sb = (lane >> 4) * 16;
    const float* wg1 = Wg1 + ((size_t)e * GH + hh) * S;
    float g1p = 0.f;
#pragma unroll
    for (int si = 0; si < 16; si++) g1p += fsh[wave][sb + si] * wg1[sb + si];
    g1p += __shfl_xor(g1p, 16, 64);
    g1p += __shfl_xor(g1p, 32, 64);
    float g1 = g1p + bg1[e * GH + hh];
    g1 = 0.5f * g1 * (1.0f + erff(g1 * 0.70710678118654752f));
    float part = g1 * Wg2[e * GH + hh];
    part += __shfl_xor(part, 1, 64);
    part += __shfl_xor(part, 2, 64);
    part += __shfl_xor(part, 4, 64);
    part += __shfl_xor(part, 8, 64);
    float g2 = part + bg2[e];
    float gate = 1.0f / (1.0f + __expf(-g2));
    float aw = 1.0f / (1.0f + __expf(-alpha[e]));
    float gm = gate * aw + (1.0f - aw);
    __syncthreads();
    fsh[wave][lane] = f * gm;
    __syncthreads();
    // QKV: lane owns rows d = lane, lane+64; per-matrix phase; float4 s-chunks
    const float* fW = fsh[wave];
    size_t wbase = (size_t)e * DE * S;
    size_t ob = (size_t)t * DE;
    {
        const float* Wm = Wq + wbase;
        float a0 = 0.f, a1 = 0.f;
#pragma unroll
        for (int sc = 0; sc < 16; sc++) {
            float4 fv = *(const float4*)(fW + sc * 4);
            float4 w0 = *(const float4*)(Wm + (size_t)lane * S + sc * 4);
            float4 w1 = *(const float4*)(Wm + (size_t)(lane + 64) * S + sc * 4);
            a0 += fv.x*w0.x + fv.y*w0.y + fv.z*w0.z + fv.w*w0.w;
            a1 += fv.x*w1.x + fv.y*w1.y + fv.z*w1.z + fv.w*w1.w;
        }
        Q[ob + lane] = a0; Q[ob + lane + 64] = a1;
    }
    {
        const float* Wm = Wk + wbase;
        float a0 = 0.f, a1 = 0.f;
#pragma unroll
        for (int sc = 0; sc < 16; sc++) {
            float4 fv = *(const float4*)(fW + sc * 4);
            float4 w0 = *(const float4*)(Wm + (size_t)lane * S + sc * 4);
            float4 w1 = *(const float4*)(Wm + (size_t)(lane + 64) * S + sc * 4);
            a0 += fv.x*w0.x + fv.y*w0.y + fv.z*w0.z + fv.w*w0.w;
            a1 += fv.x*w1.x + fv.y*w1.y + fv.z*w1.z + fv.w*w1.w;
        }
        K[ob + lane] = a0; K[ob + lane + 64] = a1;
    }
    {
        const float* Wm = Wv + wbase;
        float a0 = 0.f, a1 = 0.f;
#pragma unroll
        for (int sc = 0; sc < 16; sc++) {
            float4 fv = *(const float4*)(fW + sc * 4);
            float4 w0 = *(const float4*)(Wm + (size_t)lane * S + sc * 4);
            float4 w1 = *(const float4*)(Wm + (size_t)(lane + 64) * S + sc * 4);
            a0 += fv.x*w0.x + fv.y*w0.y + fv.z*w0.z + fv.w*w0.w;
            a1 += fv.x*w1.x + fv.y*w1.y + fv.z*w1.z + fv.w*w1.w;
        }
        V[ob + lane] = a0; V[ob + lane + 64] = a1;
    }
}

// ---- kernel 2: flash attention, block = (b,e,h,64-query chunk), wave = 16 queries,
//      lane = (query, key-quarter); butterfly merge, direct F write ----
__global__ __launch_bounds__(256) void k_attn(
    const float* __restrict__ Q, const float* __restrict__ K,
    const float* __restrict__ V, const unsigned* __restrict__ cnt,
    const unsigned* __restrict__ lst, const float* __restrict__ temp,
    float* __restrict__ F) {
    __shared__ float Ksh[KMAX][HD];       // 16 KB
    __shared__ float Vsh[KMAX][HD];       // 16 KB
    int bid = blockIdx.x;                 // ((b*8+e)*8+h)*4 + qq
    int qq = bid & 3;
    int h = (bid >> 2) & 7;
    int e = (bid >> 5) & 7;
    int b = bid >> 8;
    int c = (int)cnt[e];
    int qb = qq * 64;
    if (qb >= c) return;                  // block-uniform
    int cs = c < KMAX ? c : KMAX;
    const unsigned* L = lst + e * NTOK;
    int tid = threadIdx.x, wave = tid >> 6, lane = tid & 63;
    int q16 = lane & 15, kq = lane >> 4;
    float inv_scale = 1.0f / (4.0f * fabsf(temp[0]));

    for (int j2 = tid; j2 < cs * 4; j2 += 256) {
        int i = j2 >> 2, comp = j2 & 3;
        int nk = (int)L[i];
        size_t rb = (size_t)(b * NTOK + nk) * DE + h * HD;
        ((float4*)Ksh[i])[comp] = ((const float4*)(K + rb))[comp];
        ((float4*)Vsh[i])[comp] = ((const float4*)(V + rb))[comp];
    }
    __syncthreads();

    int cl = (cs + 3) >> 2;               // keys per lane-quarter
    int k0 = kq * cl;
    int klim = min(cs, k0 + cl);

    int qi = qb + wave * 16 + q16;
    bool valid = qi < c;
    int nq = (int)L[valid ? qi : c - 1];
    const float* qp = Q + ((size_t)(b * NTOK + nq) * DE + h * HD);
    float q[16];
#pragma unroll
    for (int d4 = 0; d4 < 4; d4++) {
        float4 qv = ((const float4*)qp)[d4];
        q[4*d4]   = qv.x * inv_scale; q[4*d4+1] = qv.y * inv_scale;
        q[4*d4+2] = qv.z * inv_scale; q[4*d4+3] = qv.w * inv_scale;
    }
    float m = -1e30f, l = 0.f;
    float acc[16];
#pragma unroll
    for (int d = 0; d < 16; d++) acc[d] = 0.f;

    for (int i0 = k0; i0 < klim; i0 += 16) {       // <=4 branchless chunks
        float sreg[16];
        float cmax = -1e30f;
#pragma unroll
        for (int j = 0; j < 16; j++) {
            int i = i0 + j;
            bool v = i < klim;
            int ii = v ? i : k0;
            const float4* kr = (const float4*)Ksh[ii];
            float4 ka = kr[0], kb = kr[1], kc = kr[2], kd = kr[3];
            float sc = q[0]*ka.x + q[1]*ka.y + q[2]*ka.z + q[3]*ka.w
                     + q[4]*kb.x + q[5]*kb.y + q[6]*kb.z + q[7]*kb.w
                     + q[8]*kc.x + q[9]*kc.y + q[10]*kc.z + q[11]*kc.w
                     + q[12]*kd.x + q[13]*kd.y + q[14]*kd.z + q[15]*kd.w;
            sc = v ? sc : -1e30f;
            sreg[j] = sc;
            cmax = fmaxf(cmax, sc);
        }
        float mn = fmaxf(m, cmax);
        float r = __expf(m - mn);
        l *= r;
#pragma unroll
        for (int d = 0; d < 16; d++) acc[d] *= r;
        m = mn;
#pragma unroll
        for (int j = 0; j < 16; j++) {
            int i = i0 + j;
            int ii = i < klim ? i : k0;
            float p = __expf(sreg[j] - m);           // 0 for invalid slots
            l += p;
            const float4* vr = (const float4*)Vsh[ii];
            float4 va = vr[0], vb = vr[1], vc = vr[2], vd = vr[3];
            acc[0] += p*va.x; acc[1] += p*va.y; acc[2] += p*va.z; acc[3] += p*va.w;
            acc[4] += p*vb.x; acc[5] += p*vb.y; acc[6] += p*vb.z; acc[7] += p*vb.w;
            acc[8] += p*vc.x; acc[9] += p*vc.y; acc[10]+= p*vc.z; acc[11]+= p*vc.w;
            acc[12]+= p*vd.x; acc[13]+= p*vd.y; acc[14]+= p*vd.z; acc[15]+= p*vd.w;
        }
    }
    for (int i = cs + kq; i < c; i += 4) {  // global tail (c>KMAX only; never normally)
        int nk = (int)L[i];
        size_t rb = (size_t)(b * NTOK + nk) * DE + h * HD;
        const float* kp = K + rb;
        float sc = 0.f;
        for (int dd = 0; dd < 16; dd++) sc += q[dd] * kp[dd];
        float mn = fmaxf(m, sc);
        float r = __expf(m - mn);
        l *= r;
#pragma unroll
        for (int d = 0; d < 16; d++) acc[d] *= r;
        m = mn;
        float p = __expf(sc - m);
        l += p;
        const float* vp = V + rb;
#pragma unroll
        for (int d = 0; d < 16; d++) acc[d] += p * vp[d];
    }
    // butterfly merge across the 4 key-quarters (lane bits 4,5)
#pragma unroll
    for (int mask = 16; mask <= 32; mask <<= 1) {
        float mo = __shfl_xor(m, mask, 64);
        float lo = __shfl_xor(l, mask, 64);
        float mn = fmaxf(m, mo);
        float e1 = __expf(m - mn), e2 = __expf(mo - mn);
        l = l * e1 + lo * e2;
#pragma unroll
        for (int d = 0; d < 16; d++) {
            float ao = __shfl_xor(acc[d], mask, 64);
            acc[d] = acc[d] * e1 + ao * e2;
        }
        m = mn;
    }
    if (lane < 16 && valid) {
        float il = 1.0f / l;
        float* op = F + (size_t)(b * NTOK + nq) * DE + h * HD;
#pragma unroll
        for (int d4 = 0; d4 < 4; d4++)
            ((float4*)op)[d4] = make_float4(acc[4*d4]*il, acc[4*d4+1]*il,
                                            acc[4*d4+2]*il, acc[4*d4+3]*il);
    }
}

// ---- kernel 3: proj, 512 threads, 8 tokens, k-split 2-way with LDS merge ----
__global__ __launch_bounds__(512) void k_proj(
    const float* __restrict__ x, const float* __restrict__ F,
    const float* __restrict__ WfT, const float* __restrict__ bf,
    float* __restrict__ out) {
    __shared__ float fr[8][DE];           // 4 KB
    __shared__ float pp[8][DF];           // 16 KB (kh=1 partials)
    int t0 = blockIdx.x * 8;
    int tid = threadIdx.x;
    if (tid < 256) ((float4*)fr)[tid] = ((const float4*)(F + (size_t)t0 * DE))[tid];
    __syncthreads();
    int kh = tid >> 8, tt = tid & 255;
    float acc0[8], acc1[8];
#pragma unroll
    for (int tk = 0; tk < 8; tk++) { acc0[tk] = 0.f; acc1[tk] = 0.f; }
    int kb = kh * 64;
#pragma unroll 4
    for (int k = kb; k < kb + 64; k++) {
        float w0 = WfT[(size_t)k * DF + tt];
        float w1 = WfT[(size_t)k * DF + tt + 256];
#pragma unroll
        for (int tk = 0; tk < 8; tk++) {
            float fv = fr[tk][k];
            acc0[tk] += fv * w0;
            acc1[tk] += fv * w1;
        }
    }
    if (kh == 1) {
#pragma unroll
        for (int tk = 0; tk < 8; tk++) {
            pp[tk][tt]       = acc0[tk];
            pp[tk][tt + 256] = acc1[tk];
        }
    }
    __syncthreads();
    if (kh == 0) {
        float b0 = bf[tt], b1 = bf[tt + 256];
#pragma unroll
        for (int tk = 0; tk < 8; tk++) {
            size_t rb = (size_t)(t0 + tk) * DF;
            out[rb + tt]       = x[rb + tt]       + b0 + acc0[tk] + pp[tk][tt];
            out[rb + tt + 256] = x[rb + tt + 256] + b1 + acc1[tk] + pp[tk][tt + 256];
        }
    }
}

extern "C" void kernel_launch(void* const* d_in, const int* in_sizes, int n_in,
                              void* d_out, int out_size, void* d_ws, size_t ws_size,
                              hipStream_t stream) {
    (void)in_sizes; (void)n_in; (void)out_size; (void)ws_size;
    const float* x     = (const float*)d_in[0];
    const float* fp    = (const float*)d_in[1];
    const float* lnw   = (const float*)d_in[2];
    const float* lnb   = (const float*)d_in[3];
    const float* alpha = (const float*)d_in[4];
    const float* Wg1   = (const float*)d_in[5];
    const float* bg1   = (const float*)d_in[6];
    const float* Wg2   = (const float*)d_in[7];
    const float* bg2   = (const float*)d_in[8];
    const float* Wq    = (const float*)d_in[9];
    const float* Wk    = (const float*)d_in[10];
    const float* Wv    = (const float*)d_in[11];
    const float* temp  = (const float*)d_in[12];
    const float* Wf    = (const float*)d_in[13];
    const float* bf    = (const float*)d_in[14];
    float* out = (float*)d_out;

    char* ws = (char*)d_ws;
    unsigned* cnt = (unsigned*)ws;                     // 1 KB
    unsigned* lst = (unsigned*)(ws + 1024);            // 32 KB
    float* Qb  = (float*)(ws + 65536);                 // 1 MB each
    float* Kb  = Qb + (size_t)B * NTOK * DE;
    float* Vb  = Kb + (size_t)B * NTOK * DE;
    float* Fb  = Vb + (size_t)B * NTOK * DE;
    float* WfT = Fb + (size_t)B * NTOK * DE;           // 256 KB

    hipLaunchKernelGGL(k_prep, dim3(536), dim3(256), 0, stream,
                       Wq, Wk, Wv, Wf, fp, x, lnw, lnb, alpha, Wg1, bg1, Wg2, bg2,
                       WfT, cnt, lst, Qb, Kb, Vb);
    hipLaunchKernelGGL(k_attn, dim3(512), dim3(256), 0, stream,
                       Qb, Kb, Vb, cnt, lst, temp, Fb);
    hipLaunchKernelGGL(k_proj, dim3(B * NTOK / 8), dim3(512), 0, stream,
                       x, Fb, WfT, bf, out);
}